// Round 2
// baseline (975.818 us; speedup 1.0000x reference)
//
#include <hip/hip_runtime.h>
#include <hip/hip_bf16.h>
#include <math.h>

#define T_STEPS 1000
#define BATCH   128
#define NH      256
#define NIC     268
#define NHD     12

// Output layout (floats), concatenated in reference return order:
// (logits_hd, logits_pc, bottleneck_acts(=y), rnn_states(=y), cell_states(=s))
#define SZ_HD (T_STEPS * BATCH * NHD)
#define SZ_PC (T_STEPS * BATCH * NH)
#define OFF_HD 0
#define OFF_PC (SZ_HD)
#define OFF_BA (OFF_PC + SZ_PC)
#define OFF_RS (OFF_BA + SZ_PC)
#define OFF_CS (OFF_RS + SZ_PC)

typedef __attribute__((ext_vector_type(8))) short short8;
typedef __attribute__((ext_vector_type(4))) float float4v;

static __device__ __forceinline__ unsigned short f32_to_bf16_bits(float v) {
    __hip_bfloat16 h = __float2bfloat16(v);
    return *reinterpret_cast<unsigned short*>(&h);
}

// ---------------------------------------------------------------------------
// Kernel 1: fused init (sigmoid embeds) + sequential recurrence, ALL IN F64.
// The spike threshold (s > 0) is chaotic: f32 accumulation error (~1e-6)
// flips ~8 spikes over 32.8M samples vs the f64 numpy reference; f64 brings
// flip probability to ~1e-8. The kernel is store-BW-bound, so f64 VALU is
// free in the shadow of the 393 MB of output stores.
// One thread per (b,h). 512 blocks x 64 threads.
// ---------------------------------------------------------------------------
__global__ __launch_bounds__(64) void recurrence_kernel(
    const float* __restrict__ x,    // [T,B,3]
    const float* __restrict__ ic,   // [B,268]
    const float* __restrict__ iw,   // [3,256]
    const float* __restrict__ l,    // [256]
    const float* __restrict__ bvec, // [256]
    const float* __restrict__ sew,  // [268,256]
    const float* __restrict__ seb,  // [256]
    const float* __restrict__ cew,  // [268,256]
    const float* __restrict__ ceb,  // [256]
    float* __restrict__ out)
{
    const int blk = blockIdx.x;            // 0..511
    const int b   = blk >> 2;              // 0..127
    const int h   = ((blk & 3) << 6) | (threadIdx.x & 63); // 0..255

    // init: h0 = sigmoid(ic @ sew + seb), c0 = sigmoid(ic @ cew + ceb)
    double ah = (double)seb[h];
    double ac = (double)ceb[h];
    const float* icrow = ic + (size_t)b * NIC;
    for (int k = 0; k < NIC; ++k) {
        const double v = (double)icrow[k];            // wave-uniform
        ah += v * (double)sew[(size_t)k * NH + h];    // coalesced across lanes
        ac += v * (double)cew[(size_t)k * NH + h];
    }
    double y = 1.0 / (1.0 + exp(-ah));
    double c = 1.0 / (1.0 + exp(-ac));

    const double lv = (double)l[h];
    const double bv = (double)bvec[h];
    const double w0 = (double)iw[h];
    const double w1 = (double)iw[NH + h];
    const double w2 = (double)iw[2 * NH + h];

    const float* xp = x + (size_t)b * 3;
    float* __restrict__ out_ba = out + OFF_BA;
    float* __restrict__ out_rs = out + OFF_RS;
    float* __restrict__ out_cs = out + OFF_CS;

    size_t o = (size_t)b * NH + h;
    for (int t = 0; t < T_STEPS; ++t) {
        const size_t xo = (size_t)t * (BATCH * 3);
        const double x0 = (double)xp[xo + 0];          // wave-uniform loads
        const double x1 = (double)xp[xo + 1];
        const double x2 = (double)xp[xo + 2];
        const double dot = x0 * w0 + x1 * w1 + x2 * w2;
        const double pre = (dot + y) + (lv * c) * (1.0 - y);
        const double s   = fmax(pre, 0.0);
        const double yn  = (s + bv > 0.0) ? 1.0 : 0.0;
        out_ba[o] = (float)yn;                         // coalesced 256B/wave
        out_rs[o] = (float)yn;
        out_cs[o] = (float)s;
        y = yn;
        c = s;                                         // carry c is the relu'd s
        o += (size_t)BATCH * NH;
    }
}

// ---------------------------------------------------------------------------
// Kernel 2: convert [pc_w | hd_w | zero-pad] to transposed bf16 Bt[n][k]
// (n in 0..271, k in 0..255), row stride 256 -> B-operand (B^T) layout.
// ---------------------------------------------------------------------------
__global__ __launch_bounds__(256) void wcvt_kernel(
    const float* __restrict__ pc_w,  // [256,256] row-major [k][n]
    const float* __restrict__ hd_w,  // [256,12]
    unsigned short* __restrict__ bt) // [272,256] bf16
{
    const int n = blockIdx.x;    // 0..271
    const int k = threadIdx.x;   // 0..255
    float v;
    if (n < NH)            v = pc_w[(size_t)k * NH + n];
    else if (n < NH + NHD) v = hd_w[(size_t)k * NHD + (n - NH)];
    else                   v = 0.0f;
    bt[(size_t)n * NH + k] = f32_to_bf16_bits(v);  // coalesced store
}

// ---------------------------------------------------------------------------
// Kernel 3: logits GEMM. Y[128000,256] (binary, read f32 from out_ba) times
// pc_w[256,256] (+pc_b) and hd_w[256,12] (+hd_b), bf16 MFMA 16x16x32.
// y in {0,1} is exact in bf16; weight bf16 rounding gives <=~0.02 absmax vs
// 0.29 / 0.078 thresholds. Block: 256 thr = 4 waves, BM=64 rows (16-row
// stripe per wave), 17 col-tiles of 16 (16 pc + 1 padded hd). K=256 in 8
// steps. A staged once in LDS; B frags loaded from L2-hot Bt.
// MFMA layouts (guide-verified): A[m=lane&15][k=quad*8+j],
// B^T[n=lane&15][k=quad*8+j], D: col=lane&15, row=quad*4+reg.
// ---------------------------------------------------------------------------
template <bool USE_WS>
__global__ __launch_bounds__(256) void gemm_kernel(
    const float* __restrict__ out_base,        // d_out (reads Y at OFF_BA)
    const unsigned short* __restrict__ bt,     // [272,256] bf16 (if USE_WS)
    const float* __restrict__ pc_w,
    const float* __restrict__ hd_w,
    const float* __restrict__ pc_b,
    const float* __restrict__ hd_b,
    float* __restrict__ out)
{
    __shared__ unsigned short Alds[64][264];   // bf16, +8 pad
    const int tid  = threadIdx.x;
    const int wave = tid >> 6;
    const int lane = tid & 63;
    const int r0   = blockIdx.x * 64;

    const float* __restrict__ Y = out_base + OFF_BA;

    // --- stage A tile: 64 rows x 256 k, f32 -> bf16 LDS ---
    for (int i = 0; i < 16; ++i) {
        const int idx = i * 256 + tid;     // float4 index 0..4095
        const int row = idx >> 6;          // 0..63
        const int kc  = (idx & 63) * 4;    // 0..252
        const float4v v = *reinterpret_cast<const float4v*>(
            Y + (size_t)(r0 + row) * NH + kc);
        const unsigned int u0 = (unsigned int)f32_to_bf16_bits(v.x) |
                                ((unsigned int)f32_to_bf16_bits(v.y) << 16);
        const unsigned int u1 = (unsigned int)f32_to_bf16_bits(v.z) |
                                ((unsigned int)f32_to_bf16_bits(v.w) << 16);
        const unsigned long long u = (unsigned long long)u0 |
                                     ((unsigned long long)u1 << 32);
        *reinterpret_cast<unsigned long long*>(&Alds[row][kc]) = u;
    }
    __syncthreads();

    const int m = lane & 15;   // col within tile / row within A stripe
    const int q = lane >> 4;   // quad

    float4v acc[17];
    for (int t = 0; t < 16; ++t) {
        const float bb = pc_b[t * 16 + m];
        acc[t] = (float4v){bb, bb, bb, bb};
    }
    {
        const float bb = (m < NHD) ? hd_b[m] : 0.0f;
        acc[16] = (float4v){bb, bb, bb, bb};
    }

    for (int ks = 0; ks < 8; ++ks) {
        const short8 a = *reinterpret_cast<const short8*>(
            &Alds[wave * 16 + m][ks * 32 + q * 8]);
#pragma unroll
        for (int t = 0; t < 17; ++t) {
            short8 bf;
            if constexpr (USE_WS) {
                bf = *reinterpret_cast<const short8*>(
                    bt + ((size_t)(t * 16 + m) * NH + ks * 32 + q * 8));
            } else {
                const int n = t * 16 + m;
#pragma unroll
                for (int j = 0; j < 8; ++j) {
                    const int kk = ks * 32 + q * 8 + j;
                    float v;
                    if (n < NH)            v = pc_w[(size_t)kk * NH + n];
                    else if (n < NH + NHD) v = hd_w[(size_t)kk * NHD + (n - NH)];
                    else                   v = 0.0f;
                    bf[j] = (short)f32_to_bf16_bits(v);
                }
            }
            acc[t] = __builtin_amdgcn_mfma_f32_16x16x32_bf16(a, bf, acc[t], 0, 0, 0);
        }
    }

    // --- epilogue ---
    float* __restrict__ out_pc = out + OFF_PC;
    float* __restrict__ out_hd = out + OFF_HD;
    const int rowb = r0 + wave * 16 + q * 4;
#pragma unroll
    for (int t = 0; t < 16; ++t) {
        const int col = t * 16 + m;
#pragma unroll
        for (int r = 0; r < 4; ++r)
            out_pc[(size_t)(rowb + r) * NH + col] = acc[t][r];
    }
    if (m < NHD) {
#pragma unroll
        for (int r = 0; r < 4; ++r)
            out_hd[(size_t)(rowb + r) * NHD + m] = acc[16][r];
    }
}

// ---------------------------------------------------------------------------
extern "C" void kernel_launch(void* const* d_in, const int* in_sizes, int n_in,
                              void* d_out, int out_size, void* d_ws, size_t ws_size,
                              hipStream_t stream) {
    const float* x    = (const float*)d_in[0];
    const float* ic   = (const float*)d_in[1];
    const float* iw   = (const float*)d_in[2];
    const float* l    = (const float*)d_in[3];
    const float* bb   = (const float*)d_in[4];
    const float* sew  = (const float*)d_in[5];
    const float* seb  = (const float*)d_in[6];
    const float* cew  = (const float*)d_in[7];
    const float* ceb  = (const float*)d_in[8];
    const float* pc_w = (const float*)d_in[9];
    const float* pc_b = (const float*)d_in[10];
    const float* hd_w = (const float*)d_in[11];
    const float* hd_b = (const float*)d_in[12];
    float* out = (float*)d_out;

    const bool use_ws = ws_size >= (size_t)(272 * 256 * 2);
    unsigned short* bt = (unsigned short*)d_ws;

    if (use_ws) {
        wcvt_kernel<<<272, 256, 0, stream>>>(pc_w, hd_w, bt);
    }
    recurrence_kernel<<<512, 64, 0, stream>>>(x, ic, iw, l, bb,
                                              sew, seb, cew, ceb, out);
    if (use_ws) {
        gemm_kernel<true><<<2000, 256, 0, stream>>>(out, bt, pc_w, hd_w,
                                                    pc_b, hd_b, out);
    } else {
        gemm_kernel<false><<<2000, 256, 0, stream>>>(out, nullptr, pc_w, hd_w,
                                                     pc_b, hd_b, out);
    }
}

// Round 3
// 808.485 us; speedup vs baseline: 1.2070x; 1.2070x over previous
//
#include <hip/hip_runtime.h>
#include <hip/hip_bf16.h>
#include <math.h>

#define T_STEPS 1000
#define BATCH   128
#define NH      256
#define NIC     268
#define NHD     12

// Output layout (floats), concatenated in reference return order:
// (logits_hd, logits_pc, bottleneck_acts(=y), rnn_states(=y), cell_states(=s))
#define SZ_HD (T_STEPS * BATCH * NHD)
#define SZ_PC (T_STEPS * BATCH * NH)
#define OFF_HD 0
#define OFF_PC (SZ_HD)
#define OFF_BA (OFF_PC + SZ_PC)
#define OFF_RS (OFF_BA + SZ_PC)
#define OFF_CS (OFF_RS + SZ_PC)

typedef __attribute__((ext_vector_type(8))) short short8;
typedef __attribute__((ext_vector_type(4))) float float4v;

static __device__ __forceinline__ unsigned short f32_to_bf16_bits(float v) {
    __hip_bfloat16 h = __float2bfloat16(v);
    return *reinterpret_cast<unsigned short*>(&h);
}

// ---------------------------------------------------------------------------
// Kernel 1: fused init (sigmoid embeds) + sequential recurrence, ALL IN F64
// (f64 matched the np reference's spike pattern exactly in R2 — keep).
// R2 post-mortem: 900 cyc/iter, 850 of them x-load latency (2 waves/CU,
// no TLP). Fix: double-buffered register prefetch of 10 timesteps (30 f32)
// one block ahead -> one latency exposure per 10 iters.
// One thread per (b,h). 512 blocks x 64 threads.
// ---------------------------------------------------------------------------
__global__ __launch_bounds__(64) void recurrence_kernel(
    const float* __restrict__ x,    // [T,B,3]
    const float* __restrict__ ic,   // [B,268]
    const float* __restrict__ iw,   // [3,256]
    const float* __restrict__ l,    // [256]
    const float* __restrict__ bvec, // [256]
    const float* __restrict__ sew,  // [268,256]
    const float* __restrict__ seb,  // [256]
    const float* __restrict__ cew,  // [268,256]
    const float* __restrict__ ceb,  // [256]
    float* __restrict__ out)
{
    const int blk = blockIdx.x;            // 0..511
    const int b   = blk >> 2;              // 0..127
    const int h   = ((blk & 3) << 6) | (threadIdx.x & 63); // 0..255

    // init: h0 = sigmoid(ic @ sew + seb), c0 = sigmoid(ic @ cew + ceb)
    // (kept bit-identical to the R2-passing version)
    double ah = (double)seb[h];
    double ac = (double)ceb[h];
    const float* icrow = ic + (size_t)b * NIC;
    for (int k = 0; k < NIC; ++k) {
        const double v = (double)icrow[k];            // wave-uniform
        ah += v * (double)sew[(size_t)k * NH + h];    // coalesced across lanes
        ac += v * (double)cew[(size_t)k * NH + h];
    }
    double y = 1.0 / (1.0 + exp(-ah));
    double c = 1.0 / (1.0 + exp(-ac));

    const double lv = (double)l[h];
    const double bv = (double)bvec[h];
    const double w0 = (double)iw[h];
    const double w1 = (double)iw[NH + h];
    const double w2 = (double)iw[2 * NH + h];

    const float* xp = x + (size_t)b * 3;
    float* __restrict__ out_ba = out + OFF_BA;
    float* __restrict__ out_rs = out + OFF_RS;
    float* __restrict__ out_cs = out + OFF_CS;

    const size_t obase = (size_t)b * NH + h;

    // --- software-pipelined main loop: U=10, explicit ping-pong buffers ---
    float bufA[30], bufB[30];

    auto pre_load = [&](float* bf, int tb) {
#pragma unroll
        for (int u = 0; u < 10; ++u) {
            const float* p = xp + (size_t)(tb + u) * (BATCH * 3);
            bf[u * 3 + 0] = p[0];
            bf[u * 3 + 1] = p[1];
            bf[u * 3 + 2] = p[2];
        }
    };

    auto comp10 = [&](const float* bf, int tb) {
#pragma unroll
        for (int u = 0; u < 10; ++u) {
            const double x0 = (double)bf[u * 3 + 0];
            const double x1 = (double)bf[u * 3 + 1];
            const double x2 = (double)bf[u * 3 + 2];
            const double dot = x0 * w0 + x1 * w1 + x2 * w2;
            const double pre = (dot + y) + (lv * c) * (1.0 - y);
            const double s   = fmax(pre, 0.0);
            const double yn  = (s + bv > 0.0) ? 1.0 : 0.0;
            const size_t o = obase + (size_t)(tb + u) * (BATCH * NH);
            out_ba[o] = (float)yn;                     // coalesced 256B/wave
            out_rs[o] = (float)yn;
            out_cs[o] = (float)s;
            y = yn;
            c = s;
        }
    };

    pre_load(bufA, 0);
    for (int tb = 0; tb < T_STEPS; tb += 20) {
        if (tb + 10 < T_STEPS) pre_load(bufB, tb + 10);
        comp10(bufA, tb);
        if (tb + 20 < T_STEPS) pre_load(bufA, tb + 20);
        comp10(bufB, tb + 10);
    }
}

// ---------------------------------------------------------------------------
// Kernel 2: convert [pc_w | hd_w | zero-pad] to transposed bf16 Bt[n][k]
// (n in 0..271, k in 0..255), row stride 256 -> B-operand (B^T) layout.
// ---------------------------------------------------------------------------
__global__ __launch_bounds__(256) void wcvt_kernel(
    const float* __restrict__ pc_w,  // [256,256] row-major [k][n]
    const float* __restrict__ hd_w,  // [256,12]
    unsigned short* __restrict__ bt) // [272,256] bf16
{
    const int n = blockIdx.x;    // 0..271
    const int k = threadIdx.x;   // 0..255
    float v;
    if (n < NH)            v = pc_w[(size_t)k * NH + n];
    else if (n < NH + NHD) v = hd_w[(size_t)k * NHD + (n - NH)];
    else                   v = 0.0f;
    bt[(size_t)n * NH + k] = f32_to_bf16_bits(v);  // coalesced store
}

// ---------------------------------------------------------------------------
// Kernel 3: logits GEMM. Y[128000,256] (binary, read f32 from out_ba) times
// pc_w[256,256] (+pc_b) and hd_w[256,12] (+hd_b), bf16 MFMA 16x16x32.
// R2 fix: per ks-step, batch all 17 B-frag loads into registers BEFORE the
// 17 MFMAs (one latency exposure per ks instead of per tile).
// Block: 256 thr = 4 waves, BM=64 rows (16-row stripe per wave),
// 17 col-tiles of 16 (16 pc + 1 padded hd). K=256 in 8 steps.
// MFMA layouts (guide-verified): A[m=lane&15][k=quad*8+j],
// B^T[n=lane&15][k=quad*8+j], D: col=lane&15, row=quad*4+reg.
// ---------------------------------------------------------------------------
template <bool USE_WS>
__global__ __launch_bounds__(256, 2) void gemm_kernel(
    const float* __restrict__ out_base,        // d_out (reads Y at OFF_BA)
    const unsigned short* __restrict__ bt,     // [272,256] bf16 (if USE_WS)
    const float* __restrict__ pc_w,
    const float* __restrict__ hd_w,
    const float* __restrict__ pc_b,
    const float* __restrict__ hd_b,
    float* __restrict__ out)
{
    __shared__ unsigned short Alds[64][264];   // bf16, +8 pad
    const int tid  = threadIdx.x;
    const int wave = tid >> 6;
    const int lane = tid & 63;
    const int r0   = blockIdx.x * 64;

    const float* __restrict__ Y = out_base + OFF_BA;

    // --- stage A tile: 64 rows x 256 k, f32 -> bf16 LDS ---
    for (int i = 0; i < 16; ++i) {
        const int idx = i * 256 + tid;     // float4 index 0..4095
        const int row = idx >> 6;          // 0..63
        const int kc  = (idx & 63) * 4;    // 0..252
        const float4v v = *reinterpret_cast<const float4v*>(
            Y + (size_t)(r0 + row) * NH + kc);
        const unsigned int u0 = (unsigned int)f32_to_bf16_bits(v.x) |
                                ((unsigned int)f32_to_bf16_bits(v.y) << 16);
        const unsigned int u1 = (unsigned int)f32_to_bf16_bits(v.z) |
                                ((unsigned int)f32_to_bf16_bits(v.w) << 16);
        const unsigned long long u = (unsigned long long)u0 |
                                     ((unsigned long long)u1 << 32);
        *reinterpret_cast<unsigned long long*>(&Alds[row][kc]) = u;
    }
    __syncthreads();

    const int m = lane & 15;   // col within tile / row within A stripe
    const int q = lane >> 4;   // quad

    float4v acc[17];
    for (int t = 0; t < 16; ++t) {
        const float bb = pc_b[t * 16 + m];
        acc[t] = (float4v){bb, bb, bb, bb};
    }
    {
        const float bb = (m < NHD) ? hd_b[m] : 0.0f;
        acc[16] = (float4v){bb, bb, bb, bb};
    }

    for (int ks = 0; ks < 8; ++ks) {
        short8 bfr[17];
        if constexpr (USE_WS) {
#pragma unroll
            for (int t = 0; t < 17; ++t)
                bfr[t] = *reinterpret_cast<const short8*>(
                    bt + ((size_t)(t * 16 + m) * NH + ks * 32 + q * 8));
        } else {
#pragma unroll
            for (int t = 0; t < 17; ++t) {
                const int n = t * 16 + m;
#pragma unroll
                for (int j = 0; j < 8; ++j) {
                    const int kk = ks * 32 + q * 8 + j;
                    float v;
                    if (n < NH)            v = pc_w[(size_t)kk * NH + n];
                    else if (n < NH + NHD) v = hd_w[(size_t)kk * NHD + (n - NH)];
                    else                   v = 0.0f;
                    bfr[t][j] = (short)f32_to_bf16_bits(v);
                }
            }
        }
        const short8 a = *reinterpret_cast<const short8*>(
            &Alds[wave * 16 + m][ks * 32 + q * 8]);
#pragma unroll
        for (int t = 0; t < 17; ++t)
            acc[t] = __builtin_amdgcn_mfma_f32_16x16x32_bf16(a, bfr[t], acc[t], 0, 0, 0);
    }

    // --- epilogue ---
    float* __restrict__ out_pc = out + OFF_PC;
    float* __restrict__ out_hd = out + OFF_HD;
    const int rowb = r0 + wave * 16 + q * 4;
#pragma unroll
    for (int t = 0; t < 16; ++t) {
        const int col = t * 16 + m;
#pragma unroll
        for (int r = 0; r < 4; ++r)
            out_pc[(size_t)(rowb + r) * NH + col] = acc[t][r];
    }
    if (m < NHD) {
#pragma unroll
        for (int r = 0; r < 4; ++r)
            out_hd[(size_t)(rowb + r) * NHD + m] = acc[16][r];
    }
}

// ---------------------------------------------------------------------------
extern "C" void kernel_launch(void* const* d_in, const int* in_sizes, int n_in,
                              void* d_out, int out_size, void* d_ws, size_t ws_size,
                              hipStream_t stream) {
    const float* x    = (const float*)d_in[0];
    const float* ic   = (const float*)d_in[1];
    const float* iw   = (const float*)d_in[2];
    const float* l    = (const float*)d_in[3];
    const float* bb   = (const float*)d_in[4];
    const float* sew  = (const float*)d_in[5];
    const float* seb  = (const float*)d_in[6];
    const float* cew  = (const float*)d_in[7];
    const float* ceb  = (const float*)d_in[8];
    const float* pc_w = (const float*)d_in[9];
    const float* pc_b = (const float*)d_in[10];
    const float* hd_w = (const float*)d_in[11];
    const float* hd_b = (const float*)d_in[12];
    float* out = (float*)d_out;

    const bool use_ws = ws_size >= (size_t)(272 * 256 * 2);
    unsigned short* bt = (unsigned short*)d_ws;

    if (use_ws) {
        wcvt_kernel<<<272, 256, 0, stream>>>(pc_w, hd_w, bt);
    }
    recurrence_kernel<<<512, 64, 0, stream>>>(x, ic, iw, l, bb,
                                              sew, seb, cew, ceb, out);
    if (use_ws) {
        gemm_kernel<true><<<2000, 256, 0, stream>>>(out, bt, pc_w, hd_w,
                                                    pc_b, hd_b, out);
    } else {
        gemm_kernel<false><<<2000, 256, 0, stream>>>(out, nullptr, pc_w, hd_w,
                                                     pc_b, hd_b, out);
    }
}